// Round 1
// baseline (4309.253 us; speedup 1.0000x reference)
//
#include <hip/hip_runtime.h>

#define D 128            // hidden dim
#define DOUT 10

typedef float f32x4 __attribute__((ext_vector_type(4)));
typedef __bf16 bf16x8 __attribute__((ext_vector_type(8)));

// ---------------- zero init (counts + stats + g_accum contiguous) ----------------
__global__ void k_zero(float4* __restrict__ p, int n4) {
    int i = blockIdx.x * 256 + threadIdx.x;
    if (i < n4) p[i] = make_float4(0.f, 0.f, 0.f, 0.f);
}

// ---------------- CSR build ----------------
__global__ void k_count(const int* __restrict__ dst, int* __restrict__ counts, int E) {
    int e = blockIdx.x * 256 + threadIdx.x;
    if (e < E) atomicAdd(&counts[dst[e]], 1);
}

__global__ void k_scan1(const int* __restrict__ cnt, int* __restrict__ offs,
                        int* __restrict__ bsum, int N) {
    __shared__ int sd[256];
    int t = threadIdx.x;
    int base = blockIdx.x * 1024 + t * 4;
    int c0 = (base + 0 < N) ? cnt[base + 0] : 0;
    int c1 = (base + 1 < N) ? cnt[base + 1] : 0;
    int c2 = (base + 2 < N) ? cnt[base + 2] : 0;
    int c3 = (base + 3 < N) ? cnt[base + 3] : 0;
    int ts = c0 + c1 + c2 + c3;
    sd[t] = ts;
    __syncthreads();
    for (int off = 1; off < 256; off <<= 1) {
        int v = (t >= off) ? sd[t - off] : 0;
        __syncthreads();
        sd[t] += v;
        __syncthreads();
    }
    int excl = sd[t] - ts;
    if (base + 0 < N) offs[base + 0] = excl;  excl += c0;
    if (base + 1 < N) offs[base + 1] = excl;  excl += c1;
    if (base + 2 < N) offs[base + 2] = excl;  excl += c2;
    if (base + 3 < N) offs[base + 3] = excl;
    if (t == 255) bsum[blockIdx.x] = sd[255];
}

__global__ void k_scan2(int* __restrict__ bsum, int nb) {
    if (threadIdx.x == 0 && blockIdx.x == 0) {
        int run = 0;
        for (int i = 0; i < nb; ++i) { int v = bsum[i]; bsum[i] = run; run += v; }
    }
}

__global__ void k_scan3(int* __restrict__ offs, const int* __restrict__ bsum,
                        int* __restrict__ cursor, int N) {
    int i = blockIdx.x * 256 + threadIdx.x;
    if (i < N) {
        int v = offs[i] + bsum[i >> 10];
        offs[i] = v;
        cursor[i] = v;
    }
}

__global__ void k_scatter(const int* __restrict__ src, const int* __restrict__ dst,
                          int* __restrict__ cursor, int* __restrict__ ebuf, int E) {
    int e = blockIdx.x * 256 + threadIdx.x;
    if (e < E) {
        int d = dst[e];
        int pos = atomicAdd(&cursor[d], 1);
        ebuf[pos] = src[e];
    }
}

// ---------------- neighbor aggregation: pooled = sum_{e:dst=v} h[src] + (1+eps)h[v] ----
__global__ void k_aggregate(const float* __restrict__ h, const int* __restrict__ ebuf,
                            const int* __restrict__ offs, const int* __restrict__ cnt,
                            const float* __restrict__ eps, int layer,
                            float* __restrict__ pooled, int M) {
    int node = blockIdx.x * 2 + (threadIdx.x >> 7);
    int c = threadIdx.x & 127;
    if (node >= M) return;
    float acc = (1.0f + eps[layer]) * h[(size_t)node * D + c];
    int s = offs[node];
    int d = cnt[node];
    for (int i = 0; i < d; ++i) {
        int srcn = ebuf[s + i];               // uniform per block-half -> scalar load
        acc += h[(size_t)srcn * D + c];
    }
    pooled[(size_t)node * D + c] = acc;
}

// ---------------- bf16-MFMA GEMM: A(Mx128) @ W(128x128) + b, in-place into A ---------
// block = 256 thr = 4 waves; block tile 128 rows; wave w: rows w*16 and w*16+64
__global__ __launch_bounds__(256) void k_gemm(float* __restrict__ A,
                                              const float* __restrict__ W,
                                              const float* __restrict__ bias, int M) {
    __shared__ bf16x8 wlds[32][64];   // frag f = ntile*4+kchunk, per-lane 8 bf16 (32 KB)
    __shared__ float blds[D];
    int tid = threadIdx.x;
    // stage W into B-fragment-swizzled LDS layout
    for (int idx = tid; idx < 16384; idx += 256) {
        int k = idx >> 7, n = idx & 127;
        float w = W[idx];
        int kk = k & 31;
        int f = ((n >> 4) << 2) | (k >> 5);
        int lane = (n & 15) | ((kk >> 3) << 4);
        int j = kk & 7;
        ((__bf16*)&wlds[f][lane])[j] = (__bf16)w;
    }
    if (tid < D) blds[tid] = bias[tid];
    __syncthreads();

    int wave = tid >> 6, lane = tid & 63;
    int m = lane & 15, quad = lane >> 4;
    long row0 = (long)blockIdx.x * 128 + wave * 16;
    long row1 = row0 + 64;
    bool v0 = row0 < M, v1 = row1 < M;

    f32x4 z = {0.f, 0.f, 0.f, 0.f};
    f32x4 acc0[8], acc1[8];
#pragma unroll
    for (int t = 0; t < 8; ++t) { acc0[t] = z; acc1[t] = z; }

    const float* a0p = A + (row0 + m) * D + quad * 8;
    const float* a1p = A + (row1 + m) * D + quad * 8;

#pragma unroll
    for (int kc = 0; kc < 4; ++kc) {
        bf16x8 af0{}, af1{};
        if (v0) {
            float4 a = *(const float4*)(a0p + kc * 32);
            float4 b = *(const float4*)(a0p + kc * 32 + 4);
            af0[0]=(__bf16)a.x; af0[1]=(__bf16)a.y; af0[2]=(__bf16)a.z; af0[3]=(__bf16)a.w;
            af0[4]=(__bf16)b.x; af0[5]=(__bf16)b.y; af0[6]=(__bf16)b.z; af0[7]=(__bf16)b.w;
        }
        if (v1) {
            float4 a = *(const float4*)(a1p + kc * 32);
            float4 b = *(const float4*)(a1p + kc * 32 + 4);
            af1[0]=(__bf16)a.x; af1[1]=(__bf16)a.y; af1[2]=(__bf16)a.z; af1[3]=(__bf16)a.w;
            af1[4]=(__bf16)b.x; af1[5]=(__bf16)b.y; af1[6]=(__bf16)b.z; af1[7]=(__bf16)b.w;
        }
#pragma unroll
        for (int t = 0; t < 8; ++t) {
            bf16x8 bf = wlds[(t << 2) | kc][lane];
            if (v0) acc0[t] = __builtin_amdgcn_mfma_f32_16x16x32_bf16(af0, bf, acc0[t], 0, 0, 0);
            if (v1) acc1[t] = __builtin_amdgcn_mfma_f32_16x16x32_bf16(af1, bf, acc1[t], 0, 0, 0);
        }
    }
    // epilogue: C/D layout col=lane&15, row=quad*4+reg
#pragma unroll
    for (int t = 0; t < 8; ++t) {
        int col = (t << 4) | m;
        float bc = blds[col];
        if (v0) {
            size_t base = (size_t)(row0 + quad * 4) * D + col;
            A[base]           = acc0[t][0] + bc;
            A[base + D]       = acc0[t][1] + bc;
            A[base + 2 * D]   = acc0[t][2] + bc;
            A[base + 3 * D]   = acc0[t][3] + bc;
        }
        if (v1) {
            size_t base = (size_t)(row1 + quad * 4) * D + col;
            A[base]           = acc1[t][0] + bc;
            A[base + D]       = acc1[t][1] + bc;
            A[base + 2 * D]   = acc1[t][2] + bc;
            A[base + 3 * D]   = acc1[t][3] + bc;
        }
    }
}

// ---------------- BN stats: per-channel sum & sumsq partials ----------------
__global__ void k_bnstats(const float* __restrict__ y, float* __restrict__ stats, int M) {
    int c = threadIdx.x & 127;
    int half = threadIdx.x >> 7;
    long r0 = (long)blockIdx.x * 256 + half;
    float s = 0.f, q = 0.f;
    for (int i = 0; i < 256; i += 2) {
        long r = r0 + i;
        if (r < M) {
            float v = y[r * D + c];
            s += v;
            q += v * v;
        }
    }
    atomicAdd(&stats[c], s);
    atomicAdd(&stats[D + c], q);
}

// ---------------- BN1 normalize + ReLU (in-place, elementwise) ----------------
__global__ void k_bnrelu(float* __restrict__ y, const float* __restrict__ stats,
                         const float* __restrict__ gamma, const float* __restrict__ beta,
                         int M) {
    long i4 = (long)blockIdx.x * 256 + threadIdx.x;
    if (i4 * 4 >= (long)M * D) return;
    int c4 = (int)(i4 & 31);
    float4 sm = ((const float4*)stats)[c4];
    float4 sq = ((const float4*)(stats + D))[c4];
    float4 g = ((const float4*)gamma)[c4];
    float4 b = ((const float4*)beta)[c4];
    float invN = 1.0f / (float)M;
    float mx = sm.x * invN, my = sm.y * invN, mz = sm.z * invN, mw = sm.w * invN;
    float rx = rsqrtf(sq.x * invN - mx * mx + 1e-5f);
    float ry = rsqrtf(sq.y * invN - my * my + 1e-5f);
    float rz = rsqrtf(sq.z * invN - mz * mz + 1e-5f);
    float rw = rsqrtf(sq.w * invN - mw * mw + 1e-5f);
    float4 v = ((float4*)y)[i4];
    v.x = fmaxf(0.f, (v.x - mx) * rx * g.x + b.x);
    v.y = fmaxf(0.f, (v.y - my) * ry * g.y + b.y);
    v.z = fmaxf(0.f, (v.z - mz) * rz * g.z + b.z);
    v.w = fmaxf(0.f, (v.w - mw) * rw * g.w + b.w);
    ((float4*)y)[i4] = v;
}

// ---------------- BN2 + ReLU + fused graph-pool accumulation ----------------
__global__ void k_bn2pool(const float* __restrict__ y, const float* __restrict__ stats,
                          const float* __restrict__ gamma, const float* __restrict__ beta,
                          const int* __restrict__ gids, const float* __restrict__ fw,
                          int layer, float* __restrict__ hout, float* __restrict__ gacc,
                          int M) {
    int c = threadIdx.x;  // 128 threads
    long base = (long)blockIdx.x * 64;
    float invN = 1.0f / (float)M;
    float mean = stats[c] * invN;
    float rstd = rsqrtf(stats[D + c] * invN - mean * mean + 1e-5f);
    float g = gamma[c], bt = beta[c], wl = fw[layer];
    int cur = -1;
    float acc = 0.f;
    for (int i = 0; i < 64; ++i) {
        long node = base + i;
        if (node >= M) break;
        float v = y[node * D + c];
        float hn = fmaxf(0.f, (v - mean) * rstd * g + bt);
        hout[node * D + c] = hn;
        int gid = gids[node];  // uniform -> scalar load
        if (gid != cur) {
            if (cur >= 0) atomicAdd(&gacc[(size_t)cur * D + c], wl * acc);
            cur = gid;
            acc = 0.f;
        }
        acc += hn;
    }
    if (cur >= 0) atomicAdd(&gacc[(size_t)cur * D + c], wl * acc);
}

// ---------------- final: out = gacc(Gx128) @ Wp(128x10) + bp ----------------
__global__ void k_final(const float* __restrict__ gacc, const float* __restrict__ Wp,
                        const float* __restrict__ bp, float* __restrict__ out) {
    __shared__ float w[D * DOUT];
    __shared__ float bb[DOUT];
    int t = threadIdx.x;
    for (int i = t; i < D * DOUT; i += blockDim.x) w[i] = Wp[i];
    if (t < DOUT) bb[t] = bp[t];
    __syncthreads();
    float acc[DOUT];
#pragma unroll
    for (int o = 0; o < DOUT; ++o) acc[o] = bb[o];
    for (int k = 0; k < D; ++k) {
        float a = gacc[(size_t)t * D + k];
#pragma unroll
        for (int o = 0; o < DOUT; ++o) acc[o] += a * w[k * DOUT + o];
    }
#pragma unroll
    for (int o = 0; o < DOUT; ++o) out[(size_t)t * DOUT + o] = acc[o];
}

extern "C" void kernel_launch(void* const* d_in, const int* in_sizes, int n_in,
                              void* d_out, int out_size, void* d_ws, size_t ws_size,
                              hipStream_t stream) {
    const float* x    = (const float*)d_in[0];
    const int* esrc   = (const int*)d_in[1];
    const int* edst   = (const int*)d_in[2];
    const int* gids   = (const int*)d_in[3];
    const float* eps  = (const float*)d_in[4];
    const float* fw   = (const float*)d_in[5];
    const float* W1   = (const float*)d_in[6];
    const float* b1   = (const float*)d_in[7];
    const float* g1   = (const float*)d_in[8];
    const float* bt1  = (const float*)d_in[9];
    const float* W2   = (const float*)d_in[10];
    const float* b2   = (const float*)d_in[11];
    const float* g2   = (const float*)d_in[12];
    const float* bt2  = (const float*)d_in[13];
    const float* Wp   = (const float*)d_in[14];
    const float* bp   = (const float*)d_in[15];
    float* out        = (float*)d_out;

    const int M = in_sizes[3];     // 100000 nodes
    const int E = in_sizes[1];     // 1600000 edges
    const int L = in_sizes[4];     // 4 layers
    const int G = out_size / DOUT; // 256 graphs

    char* ws = (char*)d_ws;
    float* bufP  = (float*)ws;  ws += (size_t)M * D * 4;
    float* bufH  = (float*)ws;  ws += (size_t)M * D * 4;
    int* ebuf    = (int*)ws;    ws += (size_t)E * 4;
    int* offs    = (int*)ws;    ws += (size_t)M * 4;
    int* cursor  = (int*)ws;    ws += (size_t)M * 4;
    int* bsum    = (int*)ws;    ws += 1024;
    // contiguous zero region: counts | stats | gacc
    int* counts  = (int*)ws;    ws += (size_t)M * 4;
    float* stats = (float*)ws;  ws += (size_t)L * 2 * 256 * 4;
    float* gacc  = (float*)ws;  ws += (size_t)G * D * 4;

    int zbytes = M * 4 + L * 2 * 256 * 4 + G * D * 4;
    int n4 = zbytes / 16;
    k_zero<<<(n4 + 255) / 256, 256, 0, stream>>>((float4*)counts, n4);

    int nscan = (M + 1023) / 1024;
    k_count<<<(E + 255) / 256, 256, 0, stream>>>(edst, counts, E);
    k_scan1<<<nscan, 256, 0, stream>>>(counts, offs, bsum, M);
    k_scan2<<<1, 64, 0, stream>>>(bsum, nscan);
    k_scan3<<<(M + 255) / 256, 256, 0, stream>>>(offs, bsum, cursor, M);
    k_scatter<<<(E + 255) / 256, 256, 0, stream>>>(esrc, edst, cursor, ebuf, E);

    int gemm_grid = (M + 127) / 128;
    int bn_grid   = (M + 255) / 256;
    int ew_grid   = (int)(((size_t)M * D / 4 + 255) / 256);
    for (int l = 0; l < L; ++l) {
        const float* hin = (l == 0) ? x : bufH;
        k_aggregate<<<(M + 1) / 2, 256, 0, stream>>>(hin, ebuf, offs, counts, eps, l, bufP, M);
        k_gemm<<<gemm_grid, 256, 0, stream>>>(bufP, W1 + (size_t)l * D * D, b1 + (size_t)l * D, M);
        k_bnstats<<<bn_grid, 256, 0, stream>>>(bufP, stats + l * 512, M);
        k_bnrelu<<<ew_grid, 256, 0, stream>>>(bufP, stats + l * 512, g1 + (size_t)l * D, bt1 + (size_t)l * D, M);
        k_gemm<<<gemm_grid, 256, 0, stream>>>(bufP, W2 + (size_t)l * D * D, b2 + (size_t)l * D, M);
        k_bnstats<<<bn_grid, 256, 0, stream>>>(bufP, stats + l * 512 + 256, M);
        k_bn2pool<<<(M + 63) / 64, 128, 0, stream>>>(bufP, stats + l * 512 + 256,
                                                     g2 + (size_t)l * D, bt2 + (size_t)l * D,
                                                     gids, fw, l, bufH, gacc, M);
    }
    k_final<<<1, G, 0, stream>>>(gacc, Wp, bp, out);
}

// Round 2
// 1098.726 us; speedup vs baseline: 3.9220x; 3.9220x over previous
//
#include <hip/hip_runtime.h>

#define D 128            // hidden dim
#define DOUT 10

typedef float f32x4 __attribute__((ext_vector_type(4)));
typedef __bf16 bf16x8 __attribute__((ext_vector_type(8)));

__device__ __forceinline__ float bf2f(unsigned short u) {
    return __uint_as_float(((unsigned int)u) << 16);
}
__device__ __forceinline__ unsigned short f2bf(float f) {
    unsigned int u = __float_as_uint(f);
    u += 0x7fffu + ((u >> 16) & 1u);
    return (unsigned short)(u >> 16);
}

// ---------------- zero init (counts + stats + gacc contiguous) ----------------
__global__ void k_zero(float4* __restrict__ p, int n4) {
    int i = blockIdx.x * 256 + threadIdx.x;
    if (i < n4) p[i] = make_float4(0.f, 0.f, 0.f, 0.f);
}

// ---------------- CSR build ----------------
__global__ void k_count(const int* __restrict__ dst, int* __restrict__ counts, int E) {
    int e = blockIdx.x * 256 + threadIdx.x;
    if (e < E) atomicAdd(&counts[dst[e]], 1);
}

__global__ void k_scan1(const int* __restrict__ cnt, int* __restrict__ offs,
                        int* __restrict__ bsum, int N) {
    __shared__ int sd[256];
    int t = threadIdx.x;
    int base = blockIdx.x * 1024 + t * 4;
    int c0 = (base + 0 < N) ? cnt[base + 0] : 0;
    int c1 = (base + 1 < N) ? cnt[base + 1] : 0;
    int c2 = (base + 2 < N) ? cnt[base + 2] : 0;
    int c3 = (base + 3 < N) ? cnt[base + 3] : 0;
    int ts = c0 + c1 + c2 + c3;
    sd[t] = ts;
    __syncthreads();
    for (int off = 1; off < 256; off <<= 1) {
        int v = (t >= off) ? sd[t - off] : 0;
        __syncthreads();
        sd[t] += v;
        __syncthreads();
    }
    int excl = sd[t] - ts;
    if (base + 0 < N) offs[base + 0] = excl;  excl += c0;
    if (base + 1 < N) offs[base + 1] = excl;  excl += c1;
    if (base + 2 < N) offs[base + 2] = excl;  excl += c2;
    if (base + 3 < N) offs[base + 3] = excl;
    if (t == 255) bsum[blockIdx.x] = sd[255];
}

__global__ void k_scan2(int* __restrict__ bsum, int nb) {
    if (threadIdx.x == 0 && blockIdx.x == 0) {
        int run = 0;
        for (int i = 0; i < nb; ++i) { int v = bsum[i]; bsum[i] = run; run += v; }
    }
}

__global__ void k_scan3(int* __restrict__ offs, const int* __restrict__ bsum,
                        int* __restrict__ cursor, int N) {
    int i = blockIdx.x * 256 + threadIdx.x;
    if (i < N) {
        int v = offs[i] + bsum[i >> 10];
        offs[i] = v;
        cursor[i] = v;
    }
}

__global__ void k_scatter(const int* __restrict__ src, const int* __restrict__ dst,
                          int* __restrict__ cursor, int* __restrict__ ebuf, int E) {
    int e = blockIdx.x * 256 + threadIdx.x;
    if (e < E) {
        int d = dst[e];
        int pos = atomicAdd(&cursor[d], 1);
        ebuf[pos] = src[e];
    }
}

// ---------------- x fp32 -> bf16 (padded rows zeroed) ----------------
__global__ void k_cvt(const float* __restrict__ x, unsigned short* __restrict__ o,
                      int M, int Mpad) {
    long e = ((long)blockIdx.x * 256 + threadIdx.x) * 4;
    if (e >= (long)Mpad * D) return;
    ushort4 r;
    if (e < (long)M * D) {
        float4 v = *(const float4*)(x + e);
        r.x = f2bf(v.x); r.y = f2bf(v.y); r.z = f2bf(v.z); r.w = f2bf(v.w);
    } else {
        r = make_ushort4(0, 0, 0, 0);
    }
    *(ushort4*)(o + e) = r;
}

// ---------------- aggregation: pooled = sum_{e:dst=v} h[src] + (1+eps)h[v] ----------
// 2 nodes per wave; 32 lanes/node; 4 bf16 channels per lane; neighbor loop unroll x4
__global__ __launch_bounds__(256) void k_aggregate(
        const unsigned short* __restrict__ h, const int* __restrict__ ebuf,
        const int* __restrict__ offs, const int* __restrict__ cnt,
        const float* __restrict__ eps, int layer,
        unsigned short* __restrict__ out, int M, int Mpad) {
    int node = blockIdx.x * 8 + (threadIdx.x >> 5);
    int c = (threadIdx.x & 31) * 4;
    if (node >= Mpad) return;
    unsigned short* op = out + (size_t)node * D + c;
    if (node >= M) { *(ushort4*)op = make_ushort4(0, 0, 0, 0); return; }
    ushort4 sv = *(const ushort4*)(h + (size_t)node * D + c);
    float e1 = 1.0f + eps[layer];
    float a0 = e1 * bf2f(sv.x), a1 = e1 * bf2f(sv.y);
    float a2 = e1 * bf2f(sv.z), a3 = e1 * bf2f(sv.w);
    int s = offs[node], d = cnt[node];
    int i = 0;
    for (; i + 4 <= d; i += 4) {
        int e0 = ebuf[s + i], ee = ebuf[s + i + 1];
        int e2 = ebuf[s + i + 2], e3 = ebuf[s + i + 3];
        ushort4 u0 = *(const ushort4*)(h + (size_t)e0 * D + c);
        ushort4 u1 = *(const ushort4*)(h + (size_t)ee * D + c);
        ushort4 u2 = *(const ushort4*)(h + (size_t)e2 * D + c);
        ushort4 u3 = *(const ushort4*)(h + (size_t)e3 * D + c);
        a0 += bf2f(u0.x) + bf2f(u1.x) + bf2f(u2.x) + bf2f(u3.x);
        a1 += bf2f(u0.y) + bf2f(u1.y) + bf2f(u2.y) + bf2f(u3.y);
        a2 += bf2f(u0.z) + bf2f(u1.z) + bf2f(u2.z) + bf2f(u3.z);
        a3 += bf2f(u0.w) + bf2f(u1.w) + bf2f(u2.w) + bf2f(u3.w);
    }
    for (; i < d; ++i) {
        int e0 = ebuf[s + i];
        ushort4 u0 = *(const ushort4*)(h + (size_t)e0 * D + c);
        a0 += bf2f(u0.x); a1 += bf2f(u0.y); a2 += bf2f(u0.z); a3 += bf2f(u0.w);
    }
    ushort4 r;
    r.x = f2bf(a0); r.y = f2bf(a1); r.z = f2bf(a2); r.w = f2bf(a3);
    *(ushort4*)op = r;
}

// ---------------- GEMM1: A(bf16, Mpad x 128) @ W + b -> O(fp32) + fused BN stats ----
// block 256 = 4 waves, 64-row tile; wave w owns rows base + w*16 .. +15
__global__ __launch_bounds__(256, 4) void k_gemm_bf(
        const unsigned short* __restrict__ A, float* __restrict__ O,
        const float* __restrict__ W, const float* __restrict__ bias,
        float* __restrict__ stats, int M) {
    __shared__ bf16x8 wlds[2048];   // frag f=ntile*4+kc, 64 lanes, 16B each (32 KB)
    __shared__ float blds[D], ssum[D], ssq[D];
    int tid = threadIdx.x;
    for (int idx = tid; idx < 2048; idx += 256) {
        int lane_s = idx & 63;
        int f = idx >> 6;
        int n = ((f >> 2) << 4) | (lane_s & 15);
        int kb = ((f & 3) << 5) | ((lane_s >> 4) << 3);
        bf16x8 fr;
#pragma unroll
        for (int j = 0; j < 8; ++j) fr[j] = (__bf16)W[(kb + j) * D + n];
        wlds[idx] = fr;
    }
    if (tid < D) { blds[tid] = bias[tid]; ssum[tid] = 0.f; ssq[tid] = 0.f; }
    __syncthreads();

    int wave = tid >> 6, lane = tid & 63;
    int m = lane & 15, quad = lane >> 4;
    int row0 = blockIdx.x * 64 + wave * 16;

    f32x4 z = {0.f, 0.f, 0.f, 0.f};
    f32x4 acc[8];
#pragma unroll
    for (int t = 0; t < 8; ++t) acc[t] = z;

    const unsigned short* ap = A + (size_t)(row0 + m) * D + (quad << 3);
#pragma unroll
    for (int kc = 0; kc < 4; ++kc) {
        bf16x8 af = *(const bf16x8*)(ap + (kc << 5));
#pragma unroll
        for (int t = 0; t < 8; ++t)
            acc[t] = __builtin_amdgcn_mfma_f32_16x16x32_bf16(
                af, wlds[(((t << 2) | kc) << 6) | lane], acc[t], 0, 0, 0);
    }

    int rbase = row0 + (quad << 2);
#pragma unroll
    for (int t = 0; t < 8; ++t) {
        int cch = (t << 4) | m;
        float bc = blds[cch];
        float s = 0.f, q = 0.f;
#pragma unroll
        for (int r = 0; r < 4; ++r) {
            int row = rbase + r;
            float v = acc[t][r] + bc;
            if (row < M) {
                O[(size_t)row * D + cch] = v;
                s += v; q += v * v;
            }
        }
        s += __shfl_xor(s, 16); s += __shfl_xor(s, 32);
        q += __shfl_xor(q, 16); q += __shfl_xor(q, 32);
        if (quad == 0) { atomicAdd(&ssum[cch], s); atomicAdd(&ssq[cch], q); }
    }
    __syncthreads();
    if (tid < D) {
        atomicAdd(&stats[tid], ssum[tid]);
        atomicAdd(&stats[D + tid], ssq[tid]);
    }
}

// ---------------- GEMM2: A(fp32) -> BN1+ReLU on the fly -> @W + b, in-place, + stats2
__global__ __launch_bounds__(256, 4) void k_gemm_bn(
        float* __restrict__ A, const float* __restrict__ W,
        const float* __restrict__ bias, const float* __restrict__ stats_in,
        const float* __restrict__ gamma, const float* __restrict__ beta,
        float* __restrict__ stats_out, float invM, int M) {
    __shared__ bf16x8 wlds[2048];
    __shared__ float blds[D], s_sc[D], s_sh[D], ssum[D], ssq[D];
    int tid = threadIdx.x;
    for (int idx = tid; idx < 2048; idx += 256) {
        int lane_s = idx & 63;
        int f = idx >> 6;
        int n = ((f >> 2) << 4) | (lane_s & 15);
        int kb = ((f & 3) << 5) | ((lane_s >> 4) << 3);
        bf16x8 fr;
#pragma unroll
        for (int j = 0; j < 8; ++j) fr[j] = (__bf16)W[(kb + j) * D + n];
        wlds[idx] = fr;
    }
    if (tid < D) {
        float mean = stats_in[tid] * invM;
        float var = stats_in[D + tid] * invM - mean * mean;
        float sc = rsqrtf(var + 1e-5f) * gamma[tid];
        s_sc[tid] = sc;
        s_sh[tid] = beta[tid] - mean * sc;
        blds[tid] = bias[tid];
        ssum[tid] = 0.f; ssq[tid] = 0.f;
    }
    __syncthreads();

    int wave = tid >> 6, lane = tid & 63;
    int m = lane & 15, quad = lane >> 4;
    int row0 = blockIdx.x * 64 + wave * 16;

    f32x4 z = {0.f, 0.f, 0.f, 0.f};
    f32x4 acc[8];
#pragma unroll
    for (int t = 0; t < 8; ++t) acc[t] = z;

    const float* ap = A + (size_t)(row0 + m) * D + (quad << 3);
#pragma unroll
    for (int kc = 0; kc < 4; ++kc) {
        int kb = (kc << 5) | (quad << 3);
        float4 p0 = *(const float4*)(ap + (kc << 5));
        float4 p1 = *(const float4*)(ap + (kc << 5) + 4);
        float4 c0 = *(const float4*)&s_sc[kb];
        float4 c1 = *(const float4*)&s_sc[kb + 4];
        float4 h0 = *(const float4*)&s_sh[kb];
        float4 h1 = *(const float4*)&s_sh[kb + 4];
        bf16x8 af;
        af[0] = (__bf16)fmaxf(0.f, fmaf(p0.x, c0.x, h0.x));
        af[1] = (__bf16)fmaxf(0.f, fmaf(p0.y, c0.y, h0.y));
        af[2] = (__bf16)fmaxf(0.f, fmaf(p0.z, c0.z, h0.z));
        af[3] = (__bf16)fmaxf(0.f, fmaf(p0.w, c0.w, h0.w));
        af[4] = (__bf16)fmaxf(0.f, fmaf(p1.x, c1.x, h1.x));
        af[5] = (__bf16)fmaxf(0.f, fmaf(p1.y, c1.y, h1.y));
        af[6] = (__bf16)fmaxf(0.f, fmaf(p1.z, c1.z, h1.z));
        af[7] = (__bf16)fmaxf(0.f, fmaf(p1.w, c1.w, h1.w));
#pragma unroll
        for (int t = 0; t < 8; ++t)
            acc[t] = __builtin_amdgcn_mfma_f32_16x16x32_bf16(
                af, wlds[(((t << 2) | kc) << 6) | lane], acc[t], 0, 0, 0);
    }

    int rbase = row0 + (quad << 2);
#pragma unroll
    for (int t = 0; t < 8; ++t) {
        int cch = (t << 4) | m;
        float bc = blds[cch];
        float s = 0.f, q = 0.f;
#pragma unroll
        for (int r = 0; r < 4; ++r) {
            int row = rbase + r;
            float v = acc[t][r] + bc;
            if (row < M) {
                A[(size_t)row * D + cch] = v;
                s += v; q += v * v;
            }
        }
        s += __shfl_xor(s, 16); s += __shfl_xor(s, 32);
        q += __shfl_xor(q, 16); q += __shfl_xor(q, 32);
        if (quad == 0) { atomicAdd(&ssum[cch], s); atomicAdd(&ssq[cch], q); }
    }
    __syncthreads();
    if (tid < D) {
        atomicAdd(&stats_out[tid], ssum[tid]);
        atomicAdd(&stats_out[D + tid], ssq[tid]);
    }
}

// ---------------- BN2 + ReLU -> bf16 h, + fused weighted graph pooling ----------------
__global__ void k_bn2pool(const float* __restrict__ y, const float* __restrict__ stats,
                          const float* __restrict__ gamma, const float* __restrict__ beta,
                          const int* __restrict__ gids, const float* __restrict__ fw,
                          int layer, unsigned short* __restrict__ hout,
                          float* __restrict__ gacc, float invM, int M) {
    int c = threadIdx.x;  // 128 threads
    long base = (long)blockIdx.x * 64;
    float mean = stats[c] * invM;
    float sc = rsqrtf(stats[D + c] * invM - mean * mean + 1e-5f) * gamma[c];
    float sh = beta[c] - mean * sc;
    float wl = fw[layer];
    int cur = -1;
    float acc = 0.f;
    for (int i = 0; i < 64; ++i) {
        long node = base + i;
        if (node >= M) break;
        float hn = fmaxf(0.f, fmaf(y[node * D + c], sc, sh));
        hout[node * D + c] = f2bf(hn);
        int gid = gids[node];
        if (gid != cur) {
            if (cur >= 0) atomicAdd(&gacc[(size_t)cur * D + c], wl * acc);
            cur = gid;
            acc = 0.f;
        }
        acc += hn;
    }
    if (cur >= 0) atomicAdd(&gacc[(size_t)cur * D + c], wl * acc);
}

// ---------------- final: out = gacc(Gx128) @ Wp(128x10) + bp ----------------
__global__ void k_final(const float* __restrict__ gacc, const float* __restrict__ Wp,
                        const float* __restrict__ bp, float* __restrict__ out) {
    __shared__ float w[D * DOUT];
    __shared__ float bb[DOUT];
    int t = threadIdx.x;
    for (int i = t; i < D * DOUT; i += blockDim.x) w[i] = Wp[i];
    if (t < DOUT) bb[t] = bp[t];
    __syncthreads();
    float acc[DOUT];
#pragma unroll
    for (int o = 0; o < DOUT; ++o) acc[o] = bb[o];
    for (int k = 0; k < D; ++k) {
        float a = gacc[(size_t)t * D + k];
#pragma unroll
        for (int o = 0; o < DOUT; ++o) acc[o] += a * w[k * DOUT + o];
    }
#pragma unroll
    for (int o = 0; o < DOUT; ++o) out[(size_t)t * DOUT + o] = acc[o];
}

extern "C" void kernel_launch(void* const* d_in, const int* in_sizes, int n_in,
                              void* d_out, int out_size, void* d_ws, size_t ws_size,
                              hipStream_t stream) {
    const float* x    = (const float*)d_in[0];
    const int* esrc   = (const int*)d_in[1];
    const int* edst   = (const int*)d_in[2];
    const int* gids   = (const int*)d_in[3];
    const float* eps  = (const float*)d_in[4];
    const float* fw   = (const float*)d_in[5];
    const float* W1   = (const float*)d_in[6];
    const float* b1   = (const float*)d_in[7];
    const float* g1   = (const float*)d_in[8];
    const float* bt1  = (const float*)d_in[9];
    const float* W2   = (const float*)d_in[10];
    const float* b2   = (const float*)d_in[11];
    const float* g2   = (const float*)d_in[12];
    const float* bt2  = (const float*)d_in[13];
    const float* Wp   = (const float*)d_in[14];
    const float* bp   = (const float*)d_in[15];
    float* out        = (float*)d_out;

    const int M = in_sizes[3];     // 100000 nodes
    const int E = in_sizes[1];     // 1600000 edges
    const int L = in_sizes[4];     // 4 layers
    const int G = out_size / DOUT; // 256 graphs
    const int Mpad = ((M + 63) / 64) * 64;
    const float invM = 1.0f / (float)M;

    char* ws = (char*)d_ws;
    unsigned short* bufP = (unsigned short*)ws; ws += (size_t)Mpad * D * 2;  // pooled bf16
    float* bufT          = (float*)ws;          ws += (size_t)Mpad * D * 4;  // MLP temp fp32
    unsigned short* bufH = (unsigned short*)ws; ws += (size_t)Mpad * D * 2;  // hidden bf16
    int* ebuf    = (int*)ws;    ws += (size_t)E * 4;
    int* offs    = (int*)ws;    ws += (size_t)M * 4;
    int* cursor  = (int*)ws;    ws += (size_t)M * 4;
    int* bsum    = (int*)ws;    ws += 1024;
    // contiguous zero region: counts | stats | gacc
    int* counts  = (int*)ws;    ws += (size_t)M * 4;
    float* stats = (float*)ws;  ws += (size_t)L * 512 * 4;   // per layer: BN1 256, BN2 256
    float* gacc  = (float*)ws;  ws += (size_t)G * D * 4;

    int zbytes = M * 4 + L * 512 * 4 + G * D * 4;
    int n4 = zbytes / 16;
    k_zero<<<(n4 + 255) / 256, 256, 0, stream>>>((float4*)counts, n4);

    int nscan = (M + 1023) / 1024;
    k_count<<<(E + 255) / 256, 256, 0, stream>>>(edst, counts, E);
    k_scan1<<<nscan, 256, 0, stream>>>(counts, offs, bsum, M);
    k_scan2<<<1, 64, 0, stream>>>(bsum, nscan);
    k_scan3<<<(M + 255) / 256, 256, 0, stream>>>(offs, bsum, cursor, M);
    k_scatter<<<(E + 255) / 256, 256, 0, stream>>>(esrc, edst, cursor, ebuf, E);

    k_cvt<<<(Mpad * (D / 4) + 255) / 256, 256, 0, stream>>>(x, bufH, M, Mpad);

    int gemm_grid = Mpad / 64;
    int agg_grid  = Mpad / 8;
    int pool_grid = (M + 63) / 64;
    for (int l = 0; l < L; ++l) {
        float* st1 = stats + (size_t)l * 512;
        float* st2 = st1 + 256;
        k_aggregate<<<agg_grid, 256, 0, stream>>>(bufH, ebuf, offs, counts, eps, l,
                                                  bufP, M, Mpad);
        k_gemm_bf<<<gemm_grid, 256, 0, stream>>>(bufP, bufT, W1 + (size_t)l * D * D,
                                                 b1 + (size_t)l * D, st1, M);
        k_gemm_bn<<<gemm_grid, 256, 0, stream>>>(bufT, W2 + (size_t)l * D * D,
                                                 b2 + (size_t)l * D, st1,
                                                 g1 + (size_t)l * D, bt1 + (size_t)l * D,
                                                 st2, invM, M);
        k_bn2pool<<<pool_grid, 128, 0, stream>>>(bufT, st2, g2 + (size_t)l * D,
                                                 bt2 + (size_t)l * D, gids, fw, l,
                                                 bufH, gacc, invM, M);
    }
    k_final<<<1, G, 0, stream>>>(gacc, Wp, bp, out);
}